// Round 5
// baseline (124.808 us; speedup 1.0000x reference)
//
#include <hip/hip_runtime.h>
#include <math.h>

#define BB 64
#define QQ 900
#define GG 100
#define NCLS 10
#define CP1 11

#define STRIDE 960   // 64*15: every lane owns exactly KPL columns; cols 900..959 are +inf pads
#define KPL 15
#define NT 512
#define NW 8
#define QMASK 255    // ring queue; live entries <= n + 16 <= 116 < 256
#define ROUND_CAP 20000

#define NCH 8        // q-chunks per batch
#define QCH 128      // queries per chunk
#define CPB 4        // cost blocks per batch (each does 2 chunks)
#define CBLK (BB * CPB)   // 256 cost-role blocks; jv-role blocks follow

#define CLS_W 2.0f
#define L1_W 5.0f
#define GIOU_W 2.0f

struct Accum {
  double wnll, wt, l1, gl;
  int nm, counter;
  int pad[6];
};

// LDS overlay: one allocation sized to the larger role (~63 KB -> 2 blocks/CU).
union SharedU {
  struct {   // cost role
    float s_c[GG][QCH + 1];    // +1 pad: conflict-free both axes
    float s_prob[QCH * 13];
    float s_gb[GG * 4];
    int   s_gc[GG];
    float pm1[2][GG], pm2[2][GG];
    int   pj1[2][GG];
    int   sh_n;
  } c;
  struct {   // jv role
    float vl[STRIDE + 2];      // column duals (f32), <= 0
    int   p[QQ + 1];           // column -> owning row (1-based), 0 = free
    unsigned long long way64[STRIDE + 2];
    float m1l[GG + 1], m2l[GG + 1];
    int   aminl[GG + 1];
    int   s_gc[GG];
    int   queue[QMASK + 1];
    int   sh_n, sh_qtail, sh_head;
    double r0[NW], r1[NW], r2[NW], r3[NW];
    int   r4[NW];
    float s_lse[QQ], s_mx[QQ];
  } j;
};

// ---------------- single launch: 256 cost blocks + 64 jv blocks, pipelined ----------------
// Cost block (b, cpair) computes chunks {cpair, cpair+4} of batch b (cells 4-way
// g-interleaved on 512 threads; softmax + split row-min scan bit-identical to the
// verified split kernels), releases each chunk via threadfence + device-scope
// atomicAdd(done[b]). jv block b inits + computes softmax stats, spins on
// done[b]==NCH (agent acquire), then runs Phase B/C/D/E exactly as before.
__global__ __launch_bounds__(NT) void det_kernel(
    const float* __restrict__ logits, const float* __restrict__ pboxes,
    const int* __restrict__ gcls, const float* __restrict__ gboxes,
    float* __restrict__ cost, float4* __restrict__ part,
    int* __restrict__ done, Accum* acc, float* out) {
  __shared__ SharedU su;
  const int tid = threadIdx.x;

  if (blockIdx.x < CBLK) {
    // ================= cost role =================
    auto& C = su.c;
    const int b = blockIdx.x >> 2;       // batch-major: batch b's 4 blocks are adjacent
    const int cpair = blockIdx.x & 3;
    const int ql = tid & (QCH - 1);
    const int gq = tid >> 7;             // 0..3: interleaved g-quarter (g = gq + 4i)

    if (tid == 0) C.sh_n = 0;
    __syncthreads();
    for (int i = tid; i < GG * 4; i += NT) C.s_gb[i] = gboxes[b * GG * 4 + i];
    for (int i = tid; i < GG; i += NT) {
      const int v = gcls[b * GG + i];
      C.s_gc[i] = v;
      if (v >= 0) atomicAdd(&C.sh_n, 1);
    }
    __syncthreads();
    const int sn = C.sh_n;

    for (int half = 0; half < 2; ++half) {
      const int cc = cpair + half * 4;   // chunk id in [0,8)
      const int q = cc * QCH + ql;

      if (tid < QCH) {                   // softmax once per q (identical op order)
        const int qs = cc * QCH + tid;
        if (qs < QQ) {
          const float* lg = logits + ((size_t)b * QQ + qs) * CP1;
          float l[CP1];
          float mx = -1e30f;
          for (int c = 0; c < CP1; ++c) { l[c] = lg[c]; mx = fmaxf(mx, l[c]); }
          float se = 0.f;
          for (int c = 0; c < CP1; ++c) { l[c] = expf(l[c] - mx); se += l[c]; }
          const float inv = 1.0f / se;
          for (int c = 0; c < NCLS; ++c) C.s_prob[tid * 13 + c] = l[c] * inv;
        }
      }
      __syncthreads();

      float pcx = 0.f, pcy = 0.f, pw = 0.f, ph = 0.f;
      if (q < QQ) {
        const float* pb = pboxes + ((size_t)b * QQ + q) * 4;
        pcx = pb[0]; pcy = pb[1]; pw = pb[2]; ph = pb[3];
      }
      const float px1 = pcx - 0.5f * pw, py1 = pcy - 0.5f * ph;
      const float px2 = pcx + 0.5f * pw, py2 = pcy + 0.5f * ph;
      const float pa = fmaxf(px2 - px1, 0.f) * fmaxf(py2 - py1, 0.f);

      float* crow = cost + ((size_t)b * GG) * STRIDE + q;
      for (int g = gq; g < sn; g += 4) {   // cells are order-independent: any partition
        float cv = 3e38f;
        if (q < QQ) {
          int cls = C.s_gc[g];
          cls = cls < 0 ? 0 : (cls > NCLS - 1 ? NCLS - 1 : cls);
          const float ccst = -C.s_prob[ql * 13 + cls];
          const float gcx = C.s_gb[g * 4 + 0], gcy = C.s_gb[g * 4 + 1];
          const float gw  = C.s_gb[g * 4 + 2], gh2 = C.s_gb[g * 4 + 3];
          const float l1 = fabsf(pcx - gcx) + fabsf(pcy - gcy) + fabsf(pw - gw) + fabsf(ph - gh2);
          const float gx1 = gcx - 0.5f * gw, gy1 = gcy - 0.5f * gh2;
          const float gx2 = gcx + 0.5f * gw, gy2 = gcy + 0.5f * gh2;
          const float ga = fmaxf(gx2 - gx1, 0.f) * fmaxf(gy2 - gy1, 0.f);
          const float ltx = fmaxf(px1, gx1), lty = fmaxf(py1, gy1);
          const float rbx = fminf(px2, gx2), rby = fminf(py2, gy2);
          const float iw = fmaxf(rbx - ltx, 0.f), ih = fmaxf(rby - lty, 0.f);
          const float inter = iw * ih;
          const float uni = pa + ga - inter;
          const float iou = inter / fmaxf(uni, 1e-6f);
          const float ex1 = fminf(px1, gx1), ey1 = fminf(py1, gy1);
          const float ex2 = fmaxf(px2, gx2), ey2 = fmaxf(py2, gy2);
          const float ew = fmaxf(ex2 - ex1, 0.f), eh = fmaxf(ey2 - ey1, 0.f);
          const float enc = ew * eh;
          const float giou = iou - (enc - uni) / fmaxf(enc, 1e-6f);
          cv = CLS_W * ccst + L1_W * l1 - GIOU_W * giou;
          crow[(size_t)g * STRIDE] = cv;
        } else if (q < STRIDE) {
          crow[(size_t)g * STRIDE] = 1e30f;   // pad columns: Phase D scans them
        }
        C.s_c[g][ql] = cv;                    // 3e38 beyond QQ: excluded from mins
      }
      __syncthreads();

      // split row-min scan (tid<256 only): identical to verified split version
      {
        const int kmax = (cc == NCH - 1) ? (QQ - (NCH - 1) * QCH) : QCH;  // 4 or 128
        if (tid < 256) {
          const int sh = tid >> 7;   // 0/1 half
          const int r = tid & 127;
          if (r < sn) {
            const int k0 = sh ? 64 : 0;
            const int k1 = sh ? kmax : (kmax < 64 ? kmax : 64);
            float m1 = 3e38f, m2 = 3e38f;
            int j1 = 0x7FFFFFFF;
            for (int k = k0; k < k1; ++k) {
              const float c = C.s_c[r][k];
              if (c < m1) { m2 = m1; m1 = c; j1 = 1 + cc * QCH + k; }
              else if (c < m2) m2 = c;
            }
            C.pm1[sh][r] = m1; C.pm2[sh][r] = m2; C.pj1[sh][r] = j1;
          }
        }
        __syncthreads();
        if (tid < sn) {
          float m1 = C.pm1[0][tid], m2 = C.pm2[0][tid];
          int j1 = C.pj1[0][tid];
          const float n1 = C.pm1[1][tid], n2 = C.pm2[1][tid];
          const int i1 = C.pj1[1][tid];
          if (n1 < m1) { m2 = fminf(m1, n2); m1 = n1; j1 = i1; }   // exact merge
          else m2 = fminf(m2, n1);
          part[((size_t)b * NCH + cc) * QCH + tid] = make_float4(m1, m2, __int_as_float(j1), 0.f);
        }
      }
      __syncthreads();   // drains all vmcnt (cost+part stores) before release
      if (tid == 0) {
        __threadfence();                 // agent-scope release: flush to coherence point
        atomicAdd(&done[b], 1);          // device-scope flag
      }
    }
    return;
  }

  // ================= jv role =================
  auto& J = su.j;
  const int b = blockIdx.x - CBLK;
  const int lane = tid & 63;
  const int w = tid >> 6;

  if (tid == 0) { J.sh_n = 0; J.sh_qtail = 0; J.sh_head = 0; }
  for (int j = tid; j <= QQ; j += NT) J.p[j] = 0;
  for (int j = tid; j < STRIDE + 2; j += NT) { J.vl[j] = 0.f; J.way64[j] = 0ull; }
  if (tid < GG) J.s_gc[tid] = gcls[b * GG + tid];
  __syncthreads();
  if (tid < GG && J.s_gc[tid] >= 0) atomicAdd(&J.sh_n, 1);
  // softmax stats while cost blocks work (inputs only; same op order -> bit-identical)
  for (int qq = tid; qq < QQ; qq += NT) {
    const float* lg = logits + ((size_t)b * QQ + qq) * CP1;
    float l[CP1];
    float mx = -1e30f;
    for (int c = 0; c < CP1; ++c) { l[c] = lg[c]; mx = fmaxf(mx, l[c]); }
    float se = 0.f;
    for (int c = 0; c < CP1; ++c) se += expf(l[c] - mx);
    J.s_mx[qq] = mx;
    J.s_lse[qq] = logf(se);
  }
  __syncthreads();
  const int n = J.sh_n;
  const float* Cb = cost + (size_t)b * GG * STRIDE;

  // wait for this batch's 8 chunks (agent-scope acquire), then invalidate caches
  if (tid == 0) {
    while (__hip_atomic_load(done + b, __ATOMIC_ACQUIRE, __HIP_MEMORY_SCOPE_AGENT) < NCH)
      __builtin_amdgcn_s_sleep(2);
  }
  __syncthreads();
  __threadfence();   // acquire side: subsequent cost/part reads see released writes

  // ---- Phase B: combine per-chunk partials ----
  for (int r = tid; r < n; r += NT) {
    float m1 = 3e38f, m2 = 3e38f;
    int j1 = 0x7FFFFFFF;
#pragma unroll
    for (int ch = 0; ch < NCH; ++ch) {
      const float4 pr = part[((size_t)b * NCH + ch) * QCH + r];
      const float pm1 = pr.x, pm2 = pr.y;
      if (pm1 < m1) { m2 = fminf(m1, pm2); m1 = pm1; j1 = __float_as_int(pr.z); }
      else m2 = fminf(m2, pm1);
    }
    J.m1l[r] = m1; J.m2l[r] = m2; J.aminl[r] = j1;
  }
  __syncthreads();

  // ---- Phase C: greedy claim, contested columns go to max regret ----
  if (tid < n) {
    const float regret = J.m2l[tid] - J.m1l[tid];
    const unsigned long long key =
        ((unsigned long long)__float_as_uint(regret) << 20) | (unsigned long long)(tid + 1);
    atomicMax(&J.way64[J.aminl[tid]], key);
  }
  __syncthreads();
  if (tid < n) {
    const int j1 = J.aminl[tid];
    if ((int)(J.way64[j1] & 0xFFFFFu) == tid + 1) {
      J.p[j1] = tid + 1;
      J.vl[j1] = J.m1l[tid] - J.m2l[tid];
    } else {
      const int t0 = atomicAdd(&J.sh_qtail, 1);
      J.queue[t0 & QMASK] = tid + 1;
    }
  }
  __syncthreads();
  for (int j = tid; j < STRIDE + 2; j += NT) J.way64[j] = 0ull;   // clean slate for D
  __syncthreads();

  // ---- Phase D: 16-wide Jacobi auction (verified round 3/4 structure) ----
  {
    float pfA[KPL], pfB[KPL];
    int pfAok = 0, pfBok = 0, pfArid = 0, pfBrid = 0;
    int kround = 0;
    while (kround < ROUND_CAP) {
      const int head = J.sh_head, tail = J.sh_qtail;
      const int nq = tail - head;
      if (nq <= 0) break;
      const int take = nq < 2 * NW ? nq : 2 * NW;
      ++kround;
      const bool doA = (2 * w < take);
      const bool doB = (2 * w + 1 < take);
      int ridA = 0, ridB = 0;
      float m1A = 3e38f, m2A = 3e38f, m1B = 3e38f, m2B = 3e38f;
      int j1A = 0x7FFFFFFF, j1B = 0x7FFFFFFF;
      if (doA) {
        float rcA[KPL], rcB[KPL];
        if (pfAok) { ridA = pfArid;
#pragma unroll
          for (int k = 0; k < KPL; ++k) rcA[k] = pfA[k];
        } else {
          ridA = J.queue[(head + 2 * w) & QMASK];
          const float* Cr = Cb + (size_t)(ridA - 1) * STRIDE + lane;
#pragma unroll
          for (int k = 0; k < KPL; ++k) rcA[k] = Cr[k << 6];
        }
        if (doB) {
          if (pfBok) { ridB = pfBrid;
#pragma unroll
            for (int k = 0; k < KPL; ++k) rcB[k] = pfB[k];
          } else {
            ridB = J.queue[(head + 2 * w + 1) & QMASK];
            const float* Cr = Cb + (size_t)(ridB - 1) * STRIDE + lane;
#pragma unroll
            for (int k = 0; k < KPL; ++k) rcB[k] = Cr[k << 6];
          }
        } else {
#pragma unroll
          for (int k = 0; k < KPL; ++k) rcB[k] = 3e38f;
        }
        float nA1 = 3e38f, nA2 = 3e38f, nB1 = 3e38f, nB2 = 3e38f;
        int iA1 = 0x7FFFFFFF, iB1 = 0x7FFFFFFF;
#pragma unroll
        for (int k = 0; k < 8; ++k) {
          const float vv = J.vl[1 + lane + (k << 6)];
          const float cA = rcA[k] - vv;
          if (cA < m1A) { m2A = m1A; m1A = cA; j1A = 1 + lane + (k << 6); }
          else if (cA < m2A) m2A = cA;
          const float cB = rcB[k] - vv;
          if (cB < m1B) { m2B = m1B; m1B = cB; j1B = 1 + lane + (k << 6); }
          else if (cB < m2B) m2B = cB;
        }
#pragma unroll
        for (int k = 8; k < KPL; ++k) {
          const float vv = J.vl[1 + lane + (k << 6)];
          const float cA = rcA[k] - vv;
          if (cA < nA1) { nA2 = nA1; nA1 = cA; iA1 = 1 + lane + (k << 6); }
          else if (cA < nA2) nA2 = cA;
          const float cB = rcB[k] - vv;
          if (cB < nB1) { nB2 = nB1; nB1 = cB; iB1 = 1 + lane + (k << 6); }
          else if (cB < nB2) nB2 = cB;
        }
        if (nA1 < m1A) { m2A = fminf(m1A, nA2); m1A = nA1; j1A = iA1; }
        else m2A = fminf(m2A, nA1);
        if (nB1 < m1B) { m2B = fminf(m1B, nB2); m1B = nB1; j1B = iB1; }
        else m2B = fminf(m2B, nB1);
        for (int m = 1; m < 64; m <<= 1) {
          const float oA1 = __shfl_xor(m1A, m), oA2 = __shfl_xor(m2A, m);
          const int ojA = __shfl_xor(j1A, m);
          const float oB1 = __shfl_xor(m1B, m), oB2 = __shfl_xor(m2B, m);
          const int ojB = __shfl_xor(j1B, m);
          if (oA1 < m1A) { m2A = fminf(m1A, oA2); m1A = oA1; j1A = ojA; }
          else m2A = fminf(m2A, oA1);
          if (oB1 < m1B) { m2B = fminf(m1B, oB2); m1B = oB1; j1B = ojB; }
          else m2B = fminf(m2B, oB1);
        }
        if (lane == 0) {
          float dA = m2A - m1A;
          if (dA < 0.f) dA = 0.f;
          const unsigned long long keyA = ((unsigned long long)kround << 44) |
              ((unsigned long long)__float_as_uint(dA) << 12) | (unsigned long long)ridA;
          atomicMax(&J.way64[j1A], keyA);
          if (doB) {
            float dB = m2B - m1B;
            if (dB < 0.f) dB = 0.f;
            const unsigned long long keyB = ((unsigned long long)kround << 44) |
                ((unsigned long long)__float_as_uint(dB) << 12) | (unsigned long long)ridB;
            atomicMax(&J.way64[j1B], keyB);
          }
        }
      }
      pfAok = 0; pfBok = 0;
      {
        const int nh = head + take;
        const int pA = nh + 2 * w, pB = pA + 1;
        if (pA < tail) {
          pfArid = J.queue[pA & QMASK];
          const float* Cr = Cb + (size_t)(pfArid - 1) * STRIDE + lane;
#pragma unroll
          for (int k = 0; k < KPL; ++k) pfA[k] = Cr[k << 6];
          pfAok = 1;
        }
        if (pB < tail) {
          pfBrid = J.queue[pB & QMASK];
          const float* Cr = Cb + (size_t)(pfBrid - 1) * STRIDE + lane;
#pragma unroll
          for (int k = 0; k < KPL; ++k) pfB[k] = Cr[k << 6];
          pfBok = 1;
        }
      }
      __syncthreads();
      if (lane == 0 && doA) {
        if ((int)(J.way64[j1A] & 0xFFFu) == ridA) {
          float dA = m2A - m1A;
          if (dA < 0.f) dA = 0.f;
          const float ov = J.vl[j1A];
          float nv = ov - dA;
          if (!(nv < ov)) nv = nextafterf(ov, -3e38f);
          J.vl[j1A] = nv;
          const int k0 = J.p[j1A];
          J.p[j1A] = ridA;
          if (k0 > 0) { const int t0 = atomicAdd(&J.sh_qtail, 1); J.queue[t0 & QMASK] = k0; }
        } else {
          const int t0 = atomicAdd(&J.sh_qtail, 1);
          J.queue[t0 & QMASK] = ridA;
        }
        if (doB) {
          if ((int)(J.way64[j1B] & 0xFFFu) == ridB) {
            float dB = m2B - m1B;
            if (dB < 0.f) dB = 0.f;
            const float ov = J.vl[j1B];
            float nv = ov - dB;
            if (!(nv < ov)) nv = nextafterf(ov, -3e38f);
            J.vl[j1B] = nv;
            const int k0 = J.p[j1B];
            J.p[j1B] = ridB;
            if (k0 > 0) { const int t0 = atomicAdd(&J.sh_qtail, 1); J.queue[t0 & QMASK] = k0; }
          } else {
            const int t0 = atomicAdd(&J.sh_qtail, 1);
            J.queue[t0 & QMASK] = ridB;
          }
        }
      }
      if (tid == 0) J.sh_head = head + take;
      __syncthreads();
    }
  }
  __syncthreads();

  // ---- Phase E: fused loss ----
  double wnll = 0.0, wt = 0.0, l1d = 0.0, gld = 0.0;
  int nm = 0;
  for (int q = tid; q < QQ; q += NT) {
    const int idx = b * QQ + q;
    const int g = J.p[q + 1] - 1;
    const int t = (g >= 0) ? J.s_gc[g] : NCLS;
    const float lt = logits[(size_t)idx * CP1 + t];
    const float logp = (lt - J.s_mx[q]) - J.s_lse[q];
    const float wgt = (t == NCLS) ? 0.1f : 1.0f;
    wnll += (double)(wgt * (-logp));
    wt += (double)wgt;
    if (g >= 0) {
      nm += 1;
      const float* pb = pboxes + (size_t)idx * 4;
      const float* gb = gboxes + ((size_t)b * GG + g) * 4;
      const float pcx = pb[0], pcy = pb[1], pw = pb[2], ph = pb[3];
      const float gcx = gb[0], gcy = gb[1], gw = gb[2], gh = gb[3];
      const float l1 = fabsf(pcx - gcx) + fabsf(pcy - gcy) + fabsf(pw - gw) + fabsf(ph - gh);
      const float px1 = pcx - 0.5f * pw, py1 = pcy - 0.5f * ph;
      const float px2 = pcx + 0.5f * pw, py2 = pcy + 0.5f * ph;
      const float gx1 = gcx - 0.5f * gw, gy1 = gcy - 0.5f * gh;
      const float gx2 = gcx + 0.5f * gw, gy2 = gcy + 0.5f * gh;
      const float pa = fmaxf(px2 - px1, 0.f) * fmaxf(py2 - py1, 0.f);
      const float ga = fmaxf(gx2 - gx1, 0.f) * fmaxf(gy2 - gy1, 0.f);
      const float ltx = fmaxf(px1, gx1), lty = fmaxf(py1, gy1);
      const float rbx = fminf(px2, gx2), rby = fminf(py2, gy2);
      const float iw = fmaxf(rbx - ltx, 0.f), ih = fmaxf(rby - lty, 0.f);
      const float inter = iw * ih;
      const float uni = pa + ga - inter;
      const float iou = inter / fmaxf(uni, 1e-6f);
      const float ex1 = fminf(px1, gx1), ey1 = fminf(py1, gy1);
      const float ex2 = fmaxf(px2, gx2), ey2 = fmaxf(py2, gy2);
      const float ew = fmaxf(ex2 - ex1, 0.f), eh = fmaxf(ey2 - ey1, 0.f);
      const float enc = ew * eh;
      const float giou = iou - (enc - uni) / fmaxf(enc, 1e-6f);
      l1d += (double)l1;
      gld += (double)(1.0f - giou);
    }
  }

  for (int off = 32; off; off >>= 1) {
    wnll += __shfl_down(wnll, off);
    wt   += __shfl_down(wt, off);
    l1d  += __shfl_down(l1d, off);
    gld  += __shfl_down(gld, off);
    nm   += __shfl_down(nm, off);
  }
  if (lane == 0) { J.r0[w] = wnll; J.r1[w] = wt; J.r2[w] = l1d; J.r3[w] = gld; J.r4[w] = nm; }
  __syncthreads();
  if (tid == 0) {
    for (int x = 1; x < NW; ++x) { wnll += J.r0[x]; wt += J.r1[x]; l1d += J.r2[x]; gld += J.r3[x]; nm += J.r4[x]; }
    atomicAdd(&acc->wnll, wnll);
    atomicAdd(&acc->wt, wt);
    atomicAdd(&acc->l1, l1d);
    atomicAdd(&acc->gl, gld);
    atomicAdd(&acc->nm, nm);
    __threadfence();
    const int ticket = atomicAdd(&acc->counter, 1);
    if (ticket == BB - 1) {
      const double fw = atomicAdd(&acc->wnll, 0.0);
      const double fwt = atomicAdd(&acc->wt, 0.0);
      const double fl1 = atomicAdd(&acc->l1, 0.0);
      const double fgl = atomicAdd(&acc->gl, 0.0);
      int fnm = atomicAdd(&acc->nm, 0);
      if (fnm < 1) fnm = 1;
      const double loss = (double)CLS_W * (fw / fwt) +
                          ((double)L1_W * fl1 + (double)GIOU_W * fgl) / (double)fnm;
      out[0] = (float)loss;
    }
  }
}

extern "C" void kernel_launch(void* const* d_in, const int* in_sizes, int n_in,
                              void* d_out, int out_size, void* d_ws, size_t ws_size,
                              hipStream_t stream) {
  const float* logits = (const float*)d_in[0];
  const float* pboxes = (const float*)d_in[1];
  const int*   gcls   = (const int*)d_in[2];
  const float* gboxes = (const float*)d_in[3];

  char* ws = (char*)d_ws;
  Accum* acc = (Accum*)ws;                 // ws+0, zeroed below
  int* done = (int*)(ws + 256);            // 64 ints, zeroed below
  float4* part = (float4*)(ws + 4096);     // 64*8*128 float4 = 1 MB
  float* cost = (float*)(ws + 4096 + (size_t)BB * NCH * QCH * sizeof(float4));  // ~24.6 MB

  hipMemsetAsync(ws, 0, 4096, stream);     // acc + done flags (graph-capturable)
  det_kernel<<<CBLK + BB, NT, 0, stream>>>(logits, pboxes, gcls, gboxes,
                                           cost, part, done, acc, (float*)d_out);
}

// Round 6
// 113.510 us; speedup vs baseline: 1.0995x; 1.0995x over previous
//
#include <hip/hip_runtime.h>
#include <hip/hip_bf16.h>
#include <math.h>

#define BB 64
#define QQ 900
#define GG 100
#define NCLS 10
#define CP1 11

#define STRIDE 960   // 64*15: every lane owns exactly KPL columns; cols 900..959 are +inf pads
#define KPL 15
#define NT 512
#define NW 8
#define QMASK 255    // ring queue; live entries <= n + 2 <= 102 < 256
#define ROUND_CAP 20000

#define NCH 8        // q-chunks in cost kernel
#define QCH 128      // queries per chunk (8*128 = 1024 covers 960 stride)

#define CLS_W 2.0f
#define L1_W 5.0f
#define GIOU_W 2.0f

struct Accum {
  double wnll, wt, l1, gl;
  int nm, counter;
  int pad[6];
};

// ---------------- cost matrix + per-chunk row-min partials (verified round-4) ----------------
__global__ __launch_bounds__(256) void cost_kernel(
    const float* __restrict__ logits, const float* __restrict__ pboxes,
    const int* __restrict__ gcls, const float* __restrict__ gboxes,
    float* __restrict__ cost, float4* __restrict__ part, Accum* acc) {
  const int b = blockIdx.y;
  const int chunk = blockIdx.x;
  const int tid = threadIdx.x;
  const int ql = tid & (QCH - 1);
  const int gh = tid >> 7;               // 0/1: interleaved half (g = gh + 2i)
  const int q = chunk * QCH + ql;

  if (chunk == 0 && b == 0 && tid == 0) {
    acc->wnll = 0.0; acc->wt = 0.0; acc->l1 = 0.0; acc->gl = 0.0;
    acc->nm = 0; acc->counter = 0;
  }

  __shared__ float s_gb[GG * 4];
  __shared__ int   s_gc[GG];
  __shared__ float s_prob[QCH * 13];
  __shared__ float s_c[GG][QCH + 1];     // +1 pad: conflict-free both axes
  __shared__ float pm1[2][GG], pm2[2][GG];
  __shared__ int   pj1[2][GG];
  __shared__ int   sh_n;

  if (tid == 0) sh_n = 0;
  __syncthreads();

  for (int i = tid; i < GG * 4; i += 256) s_gb[i] = gboxes[b * GG * 4 + i];
  for (int i = tid; i < GG; i += 256) {
    const int v = gcls[b * GG + i];
    s_gc[i] = v;
    if (v >= 0) atomicAdd(&sh_n, 1);
  }

  float pcx = 0.f, pcy = 0.f, pw = 0.f, ph = 0.f;
  if (q < QQ) {
    const float* pb = pboxes + ((size_t)b * QQ + q) * 4;
    pcx = pb[0]; pcy = pb[1]; pw = pb[2]; ph = pb[3];
    if (gh == 0) {  // softmax once per q, shared with the other g-half
      const float* lg = logits + ((size_t)b * QQ + q) * CP1;
      float l[CP1];
      float mx = -1e30f;
      for (int c = 0; c < CP1; ++c) { l[c] = lg[c]; mx = fmaxf(mx, l[c]); }
      float se = 0.f;
      for (int c = 0; c < CP1; ++c) { l[c] = expf(l[c] - mx); se += l[c]; }
      const float inv = 1.0f / se;
      for (int c = 0; c < NCLS; ++c) s_prob[ql * 13 + c] = l[c] * inv;
    }
  }
  __syncthreads();
  const int sn = sh_n;

  const float px1 = pcx - 0.5f * pw, py1 = pcy - 0.5f * ph;
  const float px2 = pcx + 0.5f * pw, py2 = pcy + 0.5f * ph;
  const float pa = fmaxf(px2 - px1, 0.f) * fmaxf(py2 - py1, 0.f);

  float* crow = cost + ((size_t)b * GG) * STRIDE + q;
  for (int g = gh; g < sn; g += 2) {     // interleave: both halves busy for any n
    float cv = 3e38f;
    if (q < QQ) {
      int cls = s_gc[g];
      cls = cls < 0 ? 0 : (cls > NCLS - 1 ? NCLS - 1 : cls);
      const float cc = -s_prob[ql * 13 + cls];
      const float gcx = s_gb[g * 4 + 0], gcy = s_gb[g * 4 + 1];
      const float gw  = s_gb[g * 4 + 2], gh2 = s_gb[g * 4 + 3];
      const float l1 = fabsf(pcx - gcx) + fabsf(pcy - gcy) + fabsf(pw - gw) + fabsf(ph - gh2);
      const float gx1 = gcx - 0.5f * gw, gy1 = gcy - 0.5f * gh2;
      const float gx2 = gcx + 0.5f * gw, gy2 = gcy + 0.5f * gh2;
      const float ga = fmaxf(gx2 - gx1, 0.f) * fmaxf(gy2 - gy1, 0.f);
      const float ltx = fmaxf(px1, gx1), lty = fmaxf(py1, gy1);
      const float rbx = fminf(px2, gx2), rby = fminf(py2, gy2);
      const float iw = fmaxf(rbx - ltx, 0.f), ih = fmaxf(rby - lty, 0.f);
      const float inter = iw * ih;
      const float uni = pa + ga - inter;
      const float iou = inter / fmaxf(uni, 1e-6f);
      const float ex1 = fminf(px1, gx1), ey1 = fminf(py1, gy1);
      const float ex2 = fmaxf(px2, gx2), ey2 = fmaxf(py2, gy2);
      const float ew = fmaxf(ex2 - ex1, 0.f), eh = fmaxf(ey2 - ey1, 0.f);
      const float enc = ew * eh;
      const float giou = iou - (enc - uni) / fmaxf(enc, 1e-6f);
      cv = CLS_W * cc + L1_W * l1 - GIOU_W * giou;
      crow[(size_t)g * STRIDE] = cv;
    } else if (q < STRIDE) {
      crow[(size_t)g * STRIDE] = 1e30f;   // pad columns: Phase D scans them
    }
    s_c[g][ql] = cv;                       // 3e38 beyond QQ: excluded from mins
  }
  __syncthreads();

  // split row-min scan: half 0 covers k in [0,min(kmax,64)), half 1 covers [64,kmax)
  {
    const int kmax = (chunk == NCH - 1) ? (QQ - (NCH - 1) * QCH) : QCH;  // 4 or 128
    const int half = tid >> 7;
    const int r = tid & 127;
    if (r < sn) {
      const int k0 = half ? 64 : 0;
      const int k1 = half ? kmax : (kmax < 64 ? kmax : 64);
      float m1 = 3e38f, m2 = 3e38f;
      int j1 = 0x7FFFFFFF;
      for (int k = k0; k < k1; ++k) {
        const float c = s_c[r][k];
        if (c < m1) { m2 = m1; m1 = c; j1 = 1 + chunk * QCH + k; }
        else if (c < m2) m2 = c;
      }
      pm1[half][r] = m1; pm2[half][r] = m2; pj1[half][r] = j1;
    }
    __syncthreads();
    if (tid < sn) {
      float m1 = pm1[0][tid], m2 = pm2[0][tid];
      int j1 = pj1[0][tid];
      const float n1 = pm1[1][tid], n2 = pm2[1][tid];
      const int i1 = pj1[1][tid];
      if (n1 < m1) { m2 = fminf(m1, n2); m1 = n1; j1 = i1; }   // exact same merge as before
      else m2 = fminf(m2, n1);
      part[((size_t)b * NCH + chunk) * QCH + tid] = make_float4(m1, m2, __int_as_float(j1), 0.f);
    }
  }
}

// ---- jv: partial rowmin + regret-greedy + single-wave barrier-free auction + warming ----
__global__ __launch_bounds__(NT) void jv_kernel(
    const float* __restrict__ logits, const float* __restrict__ pboxes,
    const int* __restrict__ gcls, const float* __restrict__ gboxes,
    const float* __restrict__ cost, const float4* __restrict__ part,
    Accum* acc, float* out) {
  const int b = blockIdx.x;
  const int tid = threadIdx.x;
  const int lane = tid & 63;
  const int w = tid >> 6;

  __shared__ float vl[STRIDE + 2];      // column duals (f32), <= 0
  __shared__ int   p[QQ + 1];           // column -> owning row (1-based), 0 = free
  __shared__ unsigned long long way64[STRIDE + 2];  // Phase-C claim keys
  __shared__ float m1l[GG + 1], m2l[GG + 1];
  __shared__ int   aminl[GG + 1];
  __shared__ int   s_gc[GG];
  __shared__ int   queue[QMASK + 1];
  __shared__ int   sh_n, sh_qtail;
  __shared__ double r0[NW], r1[NW], r2[NW], r3[NW];
  __shared__ int r4[NW];
  __shared__ float s_lse[QQ], s_mx[QQ];  // Phase-E softmax stats

  if (tid == 0) { sh_n = 0; sh_qtail = 0; }
  for (int j = tid; j <= QQ; j += NT) p[j] = 0;
  for (int j = tid; j < STRIDE + 2; j += NT) { vl[j] = 0.f; way64[j] = 0ull; }
  if (tid < GG) s_gc[tid] = gcls[b * GG + tid];
  __syncthreads();
  if (tid < GG && s_gc[tid] >= 0) atomicAdd(&sh_n, 1);
  __syncthreads();
  const int n = sh_n;
  const float* Cb = cost + (size_t)b * GG * STRIDE;

  // ---- Phase B: combine per-chunk partials from cost_kernel ----
  for (int r = tid; r < n; r += NT) {
    float m1 = 3e38f, m2 = 3e38f;
    int j1 = 0x7FFFFFFF;
#pragma unroll
    for (int ch = 0; ch < NCH; ++ch) {
      const float4 pr = part[((size_t)b * NCH + ch) * QCH + r];
      const float pm1 = pr.x, pm2 = pr.y;
      if (pm1 < m1) { m2 = fminf(m1, pm2); m1 = pm1; j1 = __float_as_int(pr.z); }
      else m2 = fminf(m2, pm1);
    }
    m1l[r] = m1; m2l[r] = m2; aminl[r] = j1;
  }
  // softmax stats for Phase E (same inner op order -> bit-identical logp)
  for (int qq = tid; qq < QQ; qq += NT) {
    const float* lg = logits + ((size_t)b * QQ + qq) * CP1;
    float l[CP1];
    float mx = -1e30f;
    for (int c = 0; c < CP1; ++c) { l[c] = lg[c]; mx = fmaxf(mx, l[c]); }
    float se = 0.f;
    for (int c = 0; c < CP1; ++c) se += expf(l[c] - mx);
    s_mx[qq] = mx;
    s_lse[qq] = logf(se);
  }
  __syncthreads();

  // ---- Phase C: greedy claim, contested columns go to max regret ----
  if (tid < n) {
    const float regret = m2l[tid] - m1l[tid];   // >= 0: non-neg f32 bits are monotone
    const unsigned long long key =
        ((unsigned long long)__float_as_uint(regret) << 20) | (unsigned long long)(tid + 1);
    atomicMax(&way64[aminl[tid]], key);
  }
  __syncthreads();
  if (tid < n) {
    const int j1 = aminl[tid];
    if ((int)(way64[j1] & 0xFFFFFu) == tid + 1) {  // winner: vl[j1] = m1 - m2 (<= 0)
      p[j1] = tid + 1;
      vl[j1] = m1l[tid] - m2l[tid];
    } else {                                       // loser: queue for the auction
      const int t0 = atomicAdd(&sh_qtail, 1);
      queue[t0 & QMASK] = tid + 1;
    }
  }
  __syncthreads();

  // ---- Phase D: single-wave barrier-free auction (wave 0), 2 bids/iter;
  // waves 1-7 warm this block's cost slice into local L1/L2 (pure reads).
  if (w == 0) {
    __builtin_amdgcn_s_setprio(1);
    float v[KPL];
#pragma unroll
    for (int k = 0; k < KPL; ++k) v[k] = vl[1 + lane + (k << 6)];
    int head = 0, tail = sh_qtail, rounds = 0;

    float pfA[KPL], pfB[KPL];
    int pfApos = -1, pfBpos = -1, pfArid = 0, pfBrid = 0;

    while (head < tail && rounds < ROUND_CAP) {
      const int nq = tail - head;
      const int take = nq >= 2 ? 2 : 1;
      ++rounds;

      // fetch current rows (prefetch hit or direct)
      int ridA, ridB = 0;
      float rcA[KPL], rcB[KPL];
      if (pfApos == head) {
        ridA = pfArid;
#pragma unroll
        for (int k = 0; k < KPL; ++k) rcA[k] = pfA[k];
      } else {
        ridA = queue[head & QMASK];
        const float* Cr = Cb + (size_t)(ridA - 1) * STRIDE + lane;
#pragma unroll
        for (int k = 0; k < KPL; ++k) rcA[k] = Cr[k << 6];
      }
      if (take == 2) {
        if (pfBpos == head + 1) {
          ridB = pfBrid;
#pragma unroll
          for (int k = 0; k < KPL; ++k) rcB[k] = pfB[k];
        } else {
          ridB = queue[(head + 1) & QMASK];
          const float* Cr = Cb + (size_t)(ridB - 1) * STRIDE + lane;
#pragma unroll
          for (int k = 0; k < KPL; ++k) rcB[k] = Cr[k << 6];
        }
      } else {
#pragma unroll
        for (int k = 0; k < KPL; ++k) rcB[k] = 3e38f;   // inert slot
      }

      // issue prefetch for next iteration's positions (pre-commit tail; immutable)
      pfApos = -1; pfBpos = -1;
      {
        const int pA = head + take, pB = head + take + 1;
        if (pA < tail) {
          pfArid = queue[pA & QMASK];
          const float* Cr = Cb + (size_t)(pfArid - 1) * STRIDE + lane;
#pragma unroll
          for (int k = 0; k < KPL; ++k) pfA[k] = Cr[k << 6];
          pfApos = pA;
        }
        if (pB < tail) {
          pfBrid = queue[pB & QMASK];
          const float* Cr = Cb + (size_t)(pfBrid - 1) * STRIDE + lane;
#pragma unroll
          for (int k = 0; k < KPL; ++k) pfB[k] = Cr[k << 6];
          pfBpos = pB;
        }
      }

      // fused A/B scan: one dual read feeds both rows (ILP), two chains each
      float m1A = 3e38f, m2A = 3e38f, m1B = 3e38f, m2B = 3e38f;
      int j1A = 0x7FFFFFFF, j1B = 0x7FFFFFFF;
      float nA1 = 3e38f, nA2 = 3e38f, nB1 = 3e38f, nB2 = 3e38f;
      int iA1 = 0x7FFFFFFF, iB1 = 0x7FFFFFFF;
#pragma unroll
      for (int k = 0; k < 8; ++k) {
        const float vv = v[k];
        const float cA = rcA[k] - vv;
        if (cA < m1A) { m2A = m1A; m1A = cA; j1A = 1 + lane + (k << 6); }
        else if (cA < m2A) m2A = cA;
        const float cB = rcB[k] - vv;
        if (cB < m1B) { m2B = m1B; m1B = cB; j1B = 1 + lane + (k << 6); }
        else if (cB < m2B) m2B = cB;
      }
#pragma unroll
      for (int k = 8; k < KPL; ++k) {
        const float vv = v[k];
        const float cA = rcA[k] - vv;
        if (cA < nA1) { nA2 = nA1; nA1 = cA; iA1 = 1 + lane + (k << 6); }
        else if (cA < nA2) nA2 = cA;
        const float cB = rcB[k] - vv;
        if (cB < nB1) { nB2 = nB1; nB1 = cB; iB1 = 1 + lane + (k << 6); }
        else if (cB < nB2) nB2 = cB;
      }
      if (nA1 < m1A) { m2A = fminf(m1A, nA2); m1A = nA1; j1A = iA1; }
      else m2A = fminf(m2A, nA1);
      if (nB1 < m1B) { m2B = fminf(m1B, nB2); m1B = nB1; j1B = iB1; }
      else m2B = fminf(m2B, nB1);
      for (int m = 1; m < 64; m <<= 1) {
        const float oA1 = __shfl_xor(m1A, m), oA2 = __shfl_xor(m2A, m);
        const int ojA = __shfl_xor(j1A, m);
        const float oB1 = __shfl_xor(m1B, m), oB2 = __shfl_xor(m2B, m);
        const int ojB = __shfl_xor(j1B, m);
        if (oA1 < m1A) { m2A = fminf(m1A, oA2); m1A = oA1; j1A = ojA; }
        else m2A = fminf(m2A, oA1);
        if (oB1 < m1B) { m2B = fminf(m1B, oB2); m1B = oB1; j1B = ojB; }
        else m2B = fminf(m2B, oB1);
      }

      // commit A (always): wave-uniform values, in-order intra-wave DS ops
      {
        float dA = m2A - m1A;
        if (dA < 0.f) dA = 0.f;
        const int c0 = j1A - 1;
        if ((c0 & 63) == lane) {   // strict decrease of claimed column's dual
          const int kk = c0 >> 6;
          const float ov = v[kk];
          float nv = ov - dA;
          if (!(nv < ov)) nv = nextafterf(ov, -3e38f);
          v[kk] = nv;
        }
        const int k0 = p[j1A];     // broadcast LDS read
        p[j1A] = ridA;             // same-addr same-value write
        if (k0 > 0) { if (lane == 0) queue[tail & QMASK] = k0; tail++; }
      }
      // commit B: contested column -> exact GS order (A first, B requeues)
      if (take == 2) {
        if (j1B == j1A) {
          if (lane == 0) queue[tail & QMASK] = ridB;
          tail++;
        } else {
          float dB = m2B - m1B;
          if (dB < 0.f) dB = 0.f;
          const int c0 = j1B - 1;
          if ((c0 & 63) == lane) {
            const int kk = c0 >> 6;
            const float ov = v[kk];
            float nv = ov - dB;
            if (!(nv < ov)) nv = nextafterf(ov, -3e38f);
            v[kk] = nv;
          }
          const int k0 = p[j1B];
          p[j1B] = ridB;
          if (k0 > 0) { if (lane == 0) queue[tail & QMASK] = k0; tail++; }
        }
      }
      head += take;
    }
    __builtin_amdgcn_s_setprio(0);
  } else {
    // waves 1-7: warm this block's cost slice into local L1/L2 (read-only, kept
    // live via asm sink) — converts Phase D's serial cold misses into L2 hits.
    for (int r = w - 1; r < n; r += NW - 1) {
      const float* Cr = Cb + (size_t)r * STRIDE + lane;
      float s = 0.f;
#pragma unroll
      for (int k = 0; k < KPL; ++k) s += Cr[k << 6];
      asm volatile("" :: "v"(s));
    }
  }
  __syncthreads();

  // ---- Phase E: fused loss; softmax stats precomputed, 1 gather per query ----
  double wnll = 0.0, wt = 0.0, l1d = 0.0, gld = 0.0;
  int nm = 0;
  for (int q = tid; q < QQ; q += NT) {
    const int idx = b * QQ + q;
    const int g = p[q + 1] - 1;   // row -> gt index (valid gts are a prefix)
    const int t = (g >= 0) ? s_gc[g] : NCLS;
    const float lt = logits[(size_t)idx * CP1 + t];
    const float logp = (lt - s_mx[q]) - s_lse[q];
    const float wgt = (t == NCLS) ? 0.1f : 1.0f;
    wnll += (double)(wgt * (-logp));
    wt += (double)wgt;
    if (g >= 0) {
      nm += 1;
      const float* pb = pboxes + (size_t)idx * 4;
      const float* gb = gboxes + ((size_t)b * GG + g) * 4;
      const float pcx = pb[0], pcy = pb[1], pw = pb[2], ph = pb[3];
      const float gcx = gb[0], gcy = gb[1], gw = gb[2], gh = gb[3];
      const float l1 = fabsf(pcx - gcx) + fabsf(pcy - gcy) + fabsf(pw - gw) + fabsf(ph - gh);
      const float px1 = pcx - 0.5f * pw, py1 = pcy - 0.5f * ph;
      const float px2 = pcx + 0.5f * pw, py2 = pcy + 0.5f * ph;
      const float gx1 = gcx - 0.5f * gw, gy1 = gcy - 0.5f * gh;
      const float gx2 = gcx + 0.5f * gw, gy2 = gcy + 0.5f * gh;
      const float pa = fmaxf(px2 - px1, 0.f) * fmaxf(py2 - py1, 0.f);
      const float ga = fmaxf(gx2 - gx1, 0.f) * fmaxf(gy2 - gy1, 0.f);
      const float ltx = fmaxf(px1, gx1), lty = fmaxf(py1, gy1);
      const float rbx = fminf(px2, gx2), rby = fminf(py2, gy2);
      const float iw = fmaxf(rbx - ltx, 0.f), ih = fmaxf(rby - lty, 0.f);
      const float inter = iw * ih;
      const float uni = pa + ga - inter;
      const float iou = inter / fmaxf(uni, 1e-6f);
      const float ex1 = fminf(px1, gx1), ey1 = fminf(py1, gy1);
      const float ex2 = fmaxf(px2, gx2), ey2 = fmaxf(py2, gy2);
      const float ew = fmaxf(ex2 - ex1, 0.f), eh = fmaxf(ey2 - ey1, 0.f);
      const float enc = ew * eh;
      const float giou = iou - (enc - uni) / fmaxf(enc, 1e-6f);
      l1d += (double)l1;
      gld += (double)(1.0f - giou);
    }
  }

  for (int off = 32; off; off >>= 1) {
    wnll += __shfl_down(wnll, off);
    wt   += __shfl_down(wt, off);
    l1d  += __shfl_down(l1d, off);
    gld  += __shfl_down(gld, off);
    nm   += __shfl_down(nm, off);
  }
  if (lane == 0) { r0[w] = wnll; r1[w] = wt; r2[w] = l1d; r3[w] = gld; r4[w] = nm; }
  __syncthreads();
  if (tid == 0) {
    for (int x = 1; x < NW; ++x) { wnll += r0[x]; wt += r1[x]; l1d += r2[x]; gld += r3[x]; nm += r4[x]; }
    atomicAdd(&acc->wnll, wnll);
    atomicAdd(&acc->wt, wt);
    atomicAdd(&acc->l1, l1d);
    atomicAdd(&acc->gl, gld);
    atomicAdd(&acc->nm, nm);
    __threadfence();
    const int ticket = atomicAdd(&acc->counter, 1);
    if (ticket == BB - 1) {
      const double fw = atomicAdd(&acc->wnll, 0.0);
      const double fwt = atomicAdd(&acc->wt, 0.0);
      const double fl1 = atomicAdd(&acc->l1, 0.0);
      const double fgl = atomicAdd(&acc->gl, 0.0);
      int fnm = atomicAdd(&acc->nm, 0);
      if (fnm < 1) fnm = 1;
      const double loss = (double)CLS_W * (fw / fwt) +
                          ((double)L1_W * fl1 + (double)GIOU_W * fgl) / (double)fnm;
      out[0] = (float)loss;
    }
  }
}

extern "C" void kernel_launch(void* const* d_in, const int* in_sizes, int n_in,
                              void* d_out, int out_size, void* d_ws, size_t ws_size,
                              hipStream_t stream) {
  const float* logits = (const float*)d_in[0];
  const float* pboxes = (const float*)d_in[1];
  const int*   gcls   = (const int*)d_in[2];
  const float* gboxes = (const float*)d_in[3];

  char* ws = (char*)d_ws;
  Accum* acc = (Accum*)ws;                                  // 64 B, inited in cost_kernel
  float4* part = (float4*)(ws + 4096);                      // 64*8*128 float4 = 1 MB
  float* cost = (float*)(ws + 4096 + (size_t)BB * NCH * QCH * sizeof(float4));  // ~24.6 MB

  cost_kernel<<<dim3(NCH, BB), 256, 0, stream>>>(logits, pboxes, gcls, gboxes, cost, part, acc);
  jv_kernel<<<BB, NT, 0, stream>>>(logits, pboxes, gcls, gboxes, cost, part, acc, (float*)d_out);
}

// Round 7
// 102.818 us; speedup vs baseline: 1.2139x; 1.1040x over previous
//
#include <hip/hip_runtime.h>
#include <hip/hip_bf16.h>
#include <math.h>

#define BB 64
#define QQ 900
#define GG 100
#define NCLS 10
#define CP1 11

#define STRIDE 960   // 64*15: every lane owns exactly KPL columns; cols 900..959 are +inf pads
#define KPL 15
#define NT 512
#define NW 8
#define QMASK 255    // ring queue; live entries <= n + 16 <= 116 < 256
#define ROUND_CAP 20000

#define NCH 8        // q-chunks in cost kernel
#define QCH 128      // queries per chunk (8*128 = 1024 covers 960 stride)

#define CLS_W 2.0f
#define L1_W 5.0f
#define GIOU_W 2.0f

struct Accum {
  double wnll, wt, l1, gl;
  int nm, counter;
  int pad[6];
};

// ---------------- cost matrix + per-chunk row-min partials (verified round-4) ----------------
__global__ __launch_bounds__(256) void cost_kernel(
    const float* __restrict__ logits, const float* __restrict__ pboxes,
    const int* __restrict__ gcls, const float* __restrict__ gboxes,
    float* __restrict__ cost, float4* __restrict__ part, Accum* acc) {
  const int b = blockIdx.y;
  const int chunk = blockIdx.x;
  const int tid = threadIdx.x;
  const int ql = tid & (QCH - 1);
  const int gh = tid >> 7;               // 0/1: interleaved half (g = gh + 2i)
  const int q = chunk * QCH + ql;

  if (chunk == 0 && b == 0 && tid == 0) {
    acc->wnll = 0.0; acc->wt = 0.0; acc->l1 = 0.0; acc->gl = 0.0;
    acc->nm = 0; acc->counter = 0;
  }

  __shared__ float s_gb[GG * 4];
  __shared__ int   s_gc[GG];
  __shared__ float s_prob[QCH * 13];
  __shared__ float s_c[GG][QCH + 1];     // +1 pad: conflict-free both axes
  __shared__ float pm1[2][GG], pm2[2][GG];
  __shared__ int   pj1[2][GG];
  __shared__ int   sh_n;

  if (tid == 0) sh_n = 0;
  __syncthreads();

  for (int i = tid; i < GG * 4; i += 256) s_gb[i] = gboxes[b * GG * 4 + i];
  for (int i = tid; i < GG; i += 256) {
    const int v = gcls[b * GG + i];
    s_gc[i] = v;
    if (v >= 0) atomicAdd(&sh_n, 1);
  }

  float pcx = 0.f, pcy = 0.f, pw = 0.f, ph = 0.f;
  if (q < QQ) {
    const float* pb = pboxes + ((size_t)b * QQ + q) * 4;
    pcx = pb[0]; pcy = pb[1]; pw = pb[2]; ph = pb[3];
    if (gh == 0) {  // softmax once per q, shared with the other g-half
      const float* lg = logits + ((size_t)b * QQ + q) * CP1;
      float l[CP1];
      float mx = -1e30f;
      for (int c = 0; c < CP1; ++c) { l[c] = lg[c]; mx = fmaxf(mx, l[c]); }
      float se = 0.f;
      for (int c = 0; c < CP1; ++c) { l[c] = expf(l[c] - mx); se += l[c]; }
      const float inv = 1.0f / se;
      for (int c = 0; c < NCLS; ++c) s_prob[ql * 13 + c] = l[c] * inv;
    }
  }
  __syncthreads();
  const int sn = sh_n;

  const float px1 = pcx - 0.5f * pw, py1 = pcy - 0.5f * ph;
  const float px2 = pcx + 0.5f * pw, py2 = pcy + 0.5f * ph;
  const float pa = fmaxf(px2 - px1, 0.f) * fmaxf(py2 - py1, 0.f);

  float* crow = cost + ((size_t)b * GG) * STRIDE + q;
  for (int g = gh; g < sn; g += 2) {     // interleave: both halves busy for any n
    float cv = 3e38f;
    if (q < QQ) {
      int cls = s_gc[g];
      cls = cls < 0 ? 0 : (cls > NCLS - 1 ? NCLS - 1 : cls);
      const float cc = -s_prob[ql * 13 + cls];
      const float gcx = s_gb[g * 4 + 0], gcy = s_gb[g * 4 + 1];
      const float gw  = s_gb[g * 4 + 2], gh2 = s_gb[g * 4 + 3];
      const float l1 = fabsf(pcx - gcx) + fabsf(pcy - gcy) + fabsf(pw - gw) + fabsf(ph - gh2);
      const float gx1 = gcx - 0.5f * gw, gy1 = gcy - 0.5f * gh2;
      const float gx2 = gcx + 0.5f * gw, gy2 = gcy + 0.5f * gh2;
      const float ga = fmaxf(gx2 - gx1, 0.f) * fmaxf(gy2 - gy1, 0.f);
      const float ltx = fmaxf(px1, gx1), lty = fmaxf(py1, gy1);
      const float rbx = fminf(px2, gx2), rby = fminf(py2, gy2);
      const float iw = fmaxf(rbx - ltx, 0.f), ih = fmaxf(rby - lty, 0.f);
      const float inter = iw * ih;
      const float uni = pa + ga - inter;
      const float iou = inter / fmaxf(uni, 1e-6f);
      const float ex1 = fminf(px1, gx1), ey1 = fminf(py1, gy1);
      const float ex2 = fmaxf(px2, gx2), ey2 = fmaxf(py2, gy2);
      const float ew = fmaxf(ex2 - ex1, 0.f), eh = fmaxf(ey2 - ey1, 0.f);
      const float enc = ew * eh;
      const float giou = iou - (enc - uni) / fmaxf(enc, 1e-6f);
      cv = CLS_W * cc + L1_W * l1 - GIOU_W * giou;
      crow[(size_t)g * STRIDE] = cv;
    } else if (q < STRIDE) {
      crow[(size_t)g * STRIDE] = 1e30f;   // pad columns: Phase D scans them
    }
    s_c[g][ql] = cv;                       // 3e38 beyond QQ: excluded from mins
  }
  __syncthreads();

  // split row-min scan: half 0 covers k in [0,min(kmax,64)), half 1 covers [64,kmax)
  {
    const int kmax = (chunk == NCH - 1) ? (QQ - (NCH - 1) * QCH) : QCH;  // 4 or 128
    const int half = tid >> 7;
    const int r = tid & 127;
    if (r < sn) {
      const int k0 = half ? 64 : 0;
      const int k1 = half ? kmax : (kmax < 64 ? kmax : 64);
      float m1 = 3e38f, m2 = 3e38f;
      int j1 = 0x7FFFFFFF;
      for (int k = k0; k < k1; ++k) {
        const float c = s_c[r][k];
        if (c < m1) { m2 = m1; m1 = c; j1 = 1 + chunk * QCH + k; }
        else if (c < m2) m2 = c;
      }
      pm1[half][r] = m1; pm2[half][r] = m2; pj1[half][r] = j1;
    }
    __syncthreads();
    if (tid < sn) {
      float m1 = pm1[0][tid], m2 = pm2[0][tid];
      int j1 = pj1[0][tid];
      const float n1 = pm1[1][tid], n2 = pm2[1][tid];
      const int i1 = pj1[1][tid];
      if (n1 < m1) { m2 = fminf(m1, n2); m1 = n1; j1 = i1; }   // exact same merge as before
      else m2 = fminf(m2, n1);
      part[((size_t)b * NCH + chunk) * QCH + tid] = make_float4(m1, m2, __int_as_float(j1), 0.f);
    }
  }
}

// -- jv: rowmin + regret-greedy + Jacobi auction w/ victim-cache for displaced rows + loss --
__global__ __launch_bounds__(NT) void jv_kernel(
    const float* __restrict__ logits, const float* __restrict__ pboxes,
    const int* __restrict__ gcls, const float* __restrict__ gboxes,
    const float* __restrict__ cost, const float4* __restrict__ part,
    Accum* acc, float* out) {
  const int b = blockIdx.x;
  const int tid = threadIdx.x;
  const int lane = tid & 63;
  const int w = tid >> 6;

  __shared__ float vl[STRIDE + 2];      // column duals (f32), <= 0
  __shared__ int   p[QQ + 1];           // column -> owning row (1-based), 0 = free
  __shared__ unsigned long long way64[STRIDE + 2];  // claim keys
  __shared__ float m1l[GG + 1], m2l[GG + 1];
  __shared__ int   aminl[GG + 1];
  __shared__ int   s_gc[GG];
  __shared__ int   queue[QMASK + 1];
  __shared__ int   sh_n, sh_qtail, sh_head;
  __shared__ double r0[NW], r1[NW], r2[NW], r3[NW];
  __shared__ int r4[NW];
  __shared__ float s_lse[QQ], s_mx[QQ];  // Phase-E softmax stats
  __shared__ float cbuf[NW][STRIDE];     // victim cache: displaced-row data (immutable rows)
  __shared__ int   ctag[NW];             // victim cache tags (rid); 0 = empty

  if (tid == 0) { sh_n = 0; sh_qtail = 0; sh_head = 0; }
  if (tid < NW) ctag[tid] = 0;
  for (int j = tid; j <= QQ; j += NT) p[j] = 0;
  for (int j = tid; j < STRIDE + 2; j += NT) { vl[j] = 0.f; way64[j] = 0ull; }
  if (tid < GG) s_gc[tid] = gcls[b * GG + tid];
  __syncthreads();
  if (tid < GG && s_gc[tid] >= 0) atomicAdd(&sh_n, 1);
  __syncthreads();
  const int n = sh_n;
  const float* Cb = cost + (size_t)b * GG * STRIDE;

  // ---- Phase B: combine per-chunk partials from cost_kernel ----
  for (int r = tid; r < n; r += NT) {
    float m1 = 3e38f, m2 = 3e38f;
    int j1 = 0x7FFFFFFF;
#pragma unroll
    for (int ch = 0; ch < NCH; ++ch) {
      const float4 pr = part[((size_t)b * NCH + ch) * QCH + r];
      const float pm1 = pr.x, pm2 = pr.y;
      if (pm1 < m1) { m2 = fminf(m1, pm2); m1 = pm1; j1 = __float_as_int(pr.z); }
      else m2 = fminf(m2, pm1);
    }
    m1l[r] = m1; m2l[r] = m2; aminl[r] = j1;
  }
  // softmax stats for Phase E (same inner op order -> bit-identical logp)
  for (int qq = tid; qq < QQ; qq += NT) {
    const float* lg = logits + ((size_t)b * QQ + qq) * CP1;
    float l[CP1];
    float mx = -1e30f;
    for (int c = 0; c < CP1; ++c) { l[c] = lg[c]; mx = fmaxf(mx, l[c]); }
    float se = 0.f;
    for (int c = 0; c < CP1; ++c) se += expf(l[c] - mx);
    s_mx[qq] = mx;
    s_lse[qq] = logf(se);
  }
  __syncthreads();

  // ---- Phase C: greedy claim, contested columns go to max regret ----
  if (tid < n) {
    const float regret = m2l[tid] - m1l[tid];   // >= 0: non-neg f32 bits are monotone
    const unsigned long long key =
        ((unsigned long long)__float_as_uint(regret) << 20) | (unsigned long long)(tid + 1);
    atomicMax(&way64[aminl[tid]], key);
  }
  __syncthreads();
  if (tid < n) {
    const int j1 = aminl[tid];
    if ((int)(way64[j1] & 0xFFFFFu) == tid + 1) {  // winner: vl[j1] = m1 - m2 (<= 0)
      p[j1] = tid + 1;
      vl[j1] = m1l[tid] - m2l[tid];
    } else {                                       // loser: queue for the auction
      const int t0 = atomicAdd(&sh_qtail, 1);
      queue[t0 & QMASK] = tid + 1;
    }
  }
  __syncthreads();
  // zero claim keys: Phase-D round-tagged keys must start from a clean slate
  for (int j = tid; j < STRIDE + 2; j += NT) way64[j] = 0ull;
  __syncthreads();

  // ---- Phase D: Jacobi auction. Burst rounds (take > NW): two rows per wave,
  // fused scan (r4-verified). Cascade rounds (take <= NW): ONE row per wave
  // (parallel scans) + victim-cache: the would-be-displaced row p[j1] is loaded
  // speculatively before the claim barrier and stashed to LDS; its requeued bid
  // next round hits LDS (~120cy) instead of a cold global row load (~600cy).
  // Stale stashes are always valid: rows are immutable. Math unchanged.
  {
    float pfA[KPL], pfB[KPL];
    int pfApos = -1, pfBpos = -1, pfArid = 0, pfBrid = 0;
    int kround = 0;
    while (kround < ROUND_CAP) {
      const int head = sh_head, tail = sh_qtail;   // uniform: read after barrier
      const int nq = tail - head;
      if (nq <= 0) break;
      const int take = nq < 2 * NW ? nq : 2 * NW;
      ++kround;

      if (take <= NW) {
        // ===== cascade path: one row per wave =====
        const bool doA = (w < take);
        int ridA = 0;
        float m1A = 3e38f, m2A = 3e38f;
        int j1A = 0x7FFFFFFF;
        int k0A = 0;
        float sfA[KPL];
        if (doA) {
          const int posA = head + w;
          float rcA[KPL];
          if (pfApos == posA) {
            ridA = pfArid;
#pragma unroll
            for (int k = 0; k < KPL; ++k) rcA[k] = pfA[k];
          } else {
            ridA = queue[posA & QMASK];
            const unsigned long long hit =
                __ballot((lane < NW) && (ctag[lane] == ridA));
            if (hit) {
              const int slot = __ffsll((long long)hit) - 1;
#pragma unroll
              for (int k = 0; k < KPL; ++k) rcA[k] = cbuf[slot][lane + (k << 6)];
            } else {
              const float* Cr = Cb + (size_t)(ridA - 1) * STRIDE + lane;
#pragma unroll
              for (int k = 0; k < KPL; ++k) rcA[k] = Cr[k << 6];
            }
          }
          // two-chain scan + merge (identical op order)
          float nA1 = 3e38f, nA2 = 3e38f;
          int iA1 = 0x7FFFFFFF;
#pragma unroll
          for (int k = 0; k < 8; ++k) {
            const float cA = rcA[k] - vl[1 + lane + (k << 6)];
            if (cA < m1A) { m2A = m1A; m1A = cA; j1A = 1 + lane + (k << 6); }
            else if (cA < m2A) m2A = cA;
          }
#pragma unroll
          for (int k = 8; k < KPL; ++k) {
            const float cA = rcA[k] - vl[1 + lane + (k << 6)];
            if (cA < nA1) { nA2 = nA1; nA1 = cA; iA1 = 1 + lane + (k << 6); }
            else if (cA < nA2) nA2 = cA;
          }
          if (nA1 < m1A) { m2A = fminf(m1A, nA2); m1A = nA1; j1A = iA1; }
          else m2A = fminf(m2A, nA1);
          for (int m = 1; m < 64; m <<= 1) {
            const float oA1 = __shfl_xor(m1A, m), oA2 = __shfl_xor(m2A, m);
            const int ojA = __shfl_xor(j1A, m);
            if (oA1 < m1A) { m2A = fminf(m1A, oA2); m1A = oA1; j1A = ojA; }
            else m2A = fminf(m2A, oA1);
          }
          // speculative displaced-row load: latency hides under claim+barrier+commit
          k0A = p[j1A];
          if (k0A > 0) {
            const float* Cr = Cb + (size_t)(k0A - 1) * STRIDE + lane;
#pragma unroll
            for (int k = 0; k < KPL; ++k) sfA[k] = Cr[k << 6];
          }
          if (lane == 0) {
            float dA = m2A - m1A;
            if (dA < 0.f) dA = 0.f;
            const unsigned long long keyA = ((unsigned long long)kround << 44) |
                ((unsigned long long)__float_as_uint(dA) << 12) | (unsigned long long)ridA;
            atomicMax(&way64[j1A], keyA);
          }
        }
        // positional prefetch for next round (stale-tail entries are immutable)
        pfApos = -1; pfBpos = -1;
        {
          const int nh = head + take;
          const int pA = nh + w;
          if (pA < tail) {
            pfArid = queue[pA & QMASK];
            const float* Cr = Cb + (size_t)(pfArid - 1) * STRIDE + lane;
#pragma unroll
            for (int k = 0; k < KPL; ++k) pfA[k] = Cr[k << 6];
            pfApos = pA;
          }
        }
        __syncthreads();   // all bids visible
        // stash displaced-row data (valid regardless of contest outcome)
        if (doA && k0A > 0) {
#pragma unroll
          for (int k = 0; k < KPL; ++k) cbuf[w][lane + (k << 6)] = sfA[k];
          if (lane == 0) ctag[w] = k0A;
        }
        if (lane == 0 && doA) {
          if ((int)(way64[j1A] & 0xFFFu) == ridA) {        // winner
            float dA = m2A - m1A;
            if (dA < 0.f) dA = 0.f;
            const float ov = vl[j1A];
            float nv = ov - dA;
            if (!(nv < ov)) nv = nextafterf(ov, -3e38f);   // strict decrease
            vl[j1A] = nv;
            const int k0 = p[j1A];
            p[j1A] = ridA;
            if (k0 > 0) { const int t0 = atomicAdd(&sh_qtail, 1); queue[t0 & QMASK] = k0; }
          } else {                                         // loser: requeue
            const int t0 = atomicAdd(&sh_qtail, 1);
            queue[t0 & QMASK] = ridA;
          }
        }
        if (tid == 0) sh_head = head + take;
        __syncthreads();
      } else {
        // ===== burst path: two rows per wave, fused scan (r4-verified) =====
        const bool doA = (w < take);                 // take > 8 -> always true
        const bool doB = (NW + w < take);
        int ridA = 0, ridB = 0;
        float m1A = 3e38f, m2A = 3e38f, m1B = 3e38f, m2B = 3e38f;
        int j1A = 0x7FFFFFFF, j1B = 0x7FFFFFFF;
        {
          float rcA[KPL], rcB[KPL];
          const int posA = head + w;
          if (pfApos == posA) {
            ridA = pfArid;
#pragma unroll
            for (int k = 0; k < KPL; ++k) rcA[k] = pfA[k];
          } else {
            ridA = queue[posA & QMASK];
            const float* Cr = Cb + (size_t)(ridA - 1) * STRIDE + lane;
#pragma unroll
            for (int k = 0; k < KPL; ++k) rcA[k] = Cr[k << 6];
          }
          if (doB) {
            const int posB = head + NW + w;
            if (pfBpos == posB) {
              ridB = pfBrid;
#pragma unroll
              for (int k = 0; k < KPL; ++k) rcB[k] = pfB[k];
            } else {
              ridB = queue[posB & QMASK];
              const float* Cr = Cb + (size_t)(ridB - 1) * STRIDE + lane;
#pragma unroll
              for (int k = 0; k < KPL; ++k) rcB[k] = Cr[k << 6];
            }
          } else {
#pragma unroll
            for (int k = 0; k < KPL; ++k) rcB[k] = 3e38f;   // inert slot
          }
          // fused scan: one dual read feeds both rows (ILP)
          float nA1 = 3e38f, nA2 = 3e38f, nB1 = 3e38f, nB2 = 3e38f;
          int iA1 = 0x7FFFFFFF, iB1 = 0x7FFFFFFF;
#pragma unroll
          for (int k = 0; k < 8; ++k) {
            const float vv = vl[1 + lane + (k << 6)];
            const float cA = rcA[k] - vv;
            if (cA < m1A) { m2A = m1A; m1A = cA; j1A = 1 + lane + (k << 6); }
            else if (cA < m2A) m2A = cA;
            const float cB = rcB[k] - vv;
            if (cB < m1B) { m2B = m1B; m1B = cB; j1B = 1 + lane + (k << 6); }
            else if (cB < m2B) m2B = cB;
          }
#pragma unroll
          for (int k = 8; k < KPL; ++k) {
            const float vv = vl[1 + lane + (k << 6)];
            const float cA = rcA[k] - vv;
            if (cA < nA1) { nA2 = nA1; nA1 = cA; iA1 = 1 + lane + (k << 6); }
            else if (cA < nA2) nA2 = cA;
            const float cB = rcB[k] - vv;
            if (cB < nB1) { nB2 = nB1; nB1 = cB; iB1 = 1 + lane + (k << 6); }
            else if (cB < nB2) nB2 = cB;
          }
          if (nA1 < m1A) { m2A = fminf(m1A, nA2); m1A = nA1; j1A = iA1; }
          else m2A = fminf(m2A, nA1);
          if (nB1 < m1B) { m2B = fminf(m1B, nB2); m1B = nB1; j1B = iB1; }
          else m2B = fminf(m2B, nB1);
          for (int m = 1; m < 64; m <<= 1) {
            const float oA1 = __shfl_xor(m1A, m), oA2 = __shfl_xor(m2A, m);
            const int ojA = __shfl_xor(j1A, m);
            const float oB1 = __shfl_xor(m1B, m), oB2 = __shfl_xor(m2B, m);
            const int ojB = __shfl_xor(j1B, m);
            if (oA1 < m1A) { m2A = fminf(m1A, oA2); m1A = oA1; j1A = ojA; }
            else m2A = fminf(m2A, oA1);
            if (oB1 < m1B) { m2B = fminf(m1B, oB2); m1B = oB1; j1B = ojB; }
            else m2B = fminf(m2B, oB1);
          }
          if (lane == 0) {
            float dA = m2A - m1A;
            if (dA < 0.f) dA = 0.f;
            const unsigned long long keyA = ((unsigned long long)kround << 44) |
                ((unsigned long long)__float_as_uint(dA) << 12) | (unsigned long long)ridA;
            atomicMax(&way64[j1A], keyA);
            if (doB) {
              float dB = m2B - m1B;
              if (dB < 0.f) dB = 0.f;
              const unsigned long long keyB = ((unsigned long long)kround << 44) |
                  ((unsigned long long)__float_as_uint(dB) << 12) | (unsigned long long)ridB;
              atomicMax(&way64[j1B], keyB);
            }
          }
        }
        // positional prefetch for next round
        pfApos = -1; pfBpos = -1;
        {
          const int nh = head + take;
          const int pA = nh + w, pB = nh + NW + w;
          if (pA < tail) {
            pfArid = queue[pA & QMASK];
            const float* Cr = Cb + (size_t)(pfArid - 1) * STRIDE + lane;
#pragma unroll
            for (int k = 0; k < KPL; ++k) pfA[k] = Cr[k << 6];
            pfApos = pA;
          }
          if (pB < tail) {
            pfBrid = queue[pB & QMASK];
            const float* Cr = Cb + (size_t)(pfBrid - 1) * STRIDE + lane;
#pragma unroll
            for (int k = 0; k < KPL; ++k) pfB[k] = Cr[k << 6];
            pfBpos = pB;
          }
        }
        __syncthreads();   // all bids visible
        if (lane == 0 && doA) {
          if ((int)(way64[j1A] & 0xFFFu) == ridA) {        // winner A
            float dA = m2A - m1A;
            if (dA < 0.f) dA = 0.f;
            const float ov = vl[j1A];
            float nv = ov - dA;
            if (!(nv < ov)) nv = nextafterf(ov, -3e38f);
            vl[j1A] = nv;
            const int k0 = p[j1A];
            p[j1A] = ridA;
            if (k0 > 0) { const int t0 = atomicAdd(&sh_qtail, 1); queue[t0 & QMASK] = k0; }
          } else {
            const int t0 = atomicAdd(&sh_qtail, 1);
            queue[t0 & QMASK] = ridA;
          }
          if (doB) {
            if ((int)(way64[j1B] & 0xFFFu) == ridB) {      // winner B
              float dB = m2B - m1B;
              if (dB < 0.f) dB = 0.f;
              const float ov = vl[j1B];
              float nv = ov - dB;
              if (!(nv < ov)) nv = nextafterf(ov, -3e38f);
              vl[j1B] = nv;
              const int k0 = p[j1B];
              p[j1B] = ridB;
              if (k0 > 0) { const int t0 = atomicAdd(&sh_qtail, 1); queue[t0 & QMASK] = k0; }
            } else {
              const int t0 = atomicAdd(&sh_qtail, 1);
              queue[t0 & QMASK] = ridB;
            }
          }
        }
        if (tid == 0) sh_head = head + take;
        __syncthreads();
      }
    }
  }
  __syncthreads();

  // ---- Phase E: fused loss; softmax stats precomputed, 1 gather per query ----
  double wnll = 0.0, wt = 0.0, l1d = 0.0, gld = 0.0;
  int nm = 0;
  for (int q = tid; q < QQ; q += NT) {
    const int idx = b * QQ + q;
    const int g = p[q + 1] - 1;   // row -> gt index (valid gts are a prefix)
    const int t = (g >= 0) ? s_gc[g] : NCLS;
    const float lt = logits[(size_t)idx * CP1 + t];
    const float logp = (lt - s_mx[q]) - s_lse[q];
    const float wgt = (t == NCLS) ? 0.1f : 1.0f;
    wnll += (double)(wgt * (-logp));
    wt += (double)wgt;
    if (g >= 0) {
      nm += 1;
      const float* pb = pboxes + (size_t)idx * 4;
      const float* gb = gboxes + ((size_t)b * GG + g) * 4;
      const float pcx = pb[0], pcy = pb[1], pw = pb[2], ph = pb[3];
      const float gcx = gb[0], gcy = gb[1], gw = gb[2], gh = gb[3];
      const float l1 = fabsf(pcx - gcx) + fabsf(pcy - gcy) + fabsf(pw - gw) + fabsf(ph - gh);
      const float px1 = pcx - 0.5f * pw, py1 = pcy - 0.5f * ph;
      const float px2 = pcx + 0.5f * pw, py2 = pcy + 0.5f * ph;
      const float gx1 = gcx - 0.5f * gw, gy1 = gcy - 0.5f * gh;
      const float gx2 = gcx + 0.5f * gw, gy2 = gcy + 0.5f * gh;
      const float pa = fmaxf(px2 - px1, 0.f) * fmaxf(py2 - py1, 0.f);
      const float ga = fmaxf(gx2 - gx1, 0.f) * fmaxf(gy2 - gy1, 0.f);
      const float ltx = fmaxf(px1, gx1), lty = fmaxf(py1, gy1);
      const float rbx = fminf(px2, gx2), rby = fminf(py2, gy2);
      const float iw = fmaxf(rbx - ltx, 0.f), ih = fmaxf(rby - lty, 0.f);
      const float inter = iw * ih;
      const float uni = pa + ga - inter;
      const float iou = inter / fmaxf(uni, 1e-6f);
      const float ex1 = fminf(px1, gx1), ey1 = fminf(py1, gy1);
      const float ex2 = fmaxf(px2, gx2), ey2 = fmaxf(py2, gy2);
      const float ew = fmaxf(ex2 - ex1, 0.f), eh = fmaxf(ey2 - ey1, 0.f);
      const float enc = ew * eh;
      const float giou = iou - (enc - uni) / fmaxf(enc, 1e-6f);
      l1d += (double)l1;
      gld += (double)(1.0f - giou);
    }
  }

  for (int off = 32; off; off >>= 1) {
    wnll += __shfl_down(wnll, off);
    wt   += __shfl_down(wt, off);
    l1d  += __shfl_down(l1d, off);
    gld  += __shfl_down(gld, off);
    nm   += __shfl_down(nm, off);
  }
  if (lane == 0) { r0[w] = wnll; r1[w] = wt; r2[w] = l1d; r3[w] = gld; r4[w] = nm; }
  __syncthreads();
  if (tid == 0) {
    for (int x = 1; x < NW; ++x) { wnll += r0[x]; wt += r1[x]; l1d += r2[x]; gld += r3[x]; nm += r4[x]; }
    atomicAdd(&acc->wnll, wnll);
    atomicAdd(&acc->wt, wt);
    atomicAdd(&acc->l1, l1d);
    atomicAdd(&acc->gl, gld);
    atomicAdd(&acc->nm, nm);
    __threadfence();
    const int ticket = atomicAdd(&acc->counter, 1);
    if (ticket == BB - 1) {
      const double fw = atomicAdd(&acc->wnll, 0.0);
      const double fwt = atomicAdd(&acc->wt, 0.0);
      const double fl1 = atomicAdd(&acc->l1, 0.0);
      const double fgl = atomicAdd(&acc->gl, 0.0);
      int fnm = atomicAdd(&acc->nm, 0);
      if (fnm < 1) fnm = 1;
      const double loss = (double)CLS_W * (fw / fwt) +
                          ((double)L1_W * fl1 + (double)GIOU_W * fgl) / (double)fnm;
      out[0] = (float)loss;
    }
  }
}

extern "C" void kernel_launch(void* const* d_in, const int* in_sizes, int n_in,
                              void* d_out, int out_size, void* d_ws, size_t ws_size,
                              hipStream_t stream) {
  const float* logits = (const float*)d_in[0];
  const float* pboxes = (const float*)d_in[1];
  const int*   gcls   = (const int*)d_in[2];
  const float* gboxes = (const float*)d_in[3];

  char* ws = (char*)d_ws;
  Accum* acc = (Accum*)ws;                                  // 64 B, inited in cost_kernel
  float4* part = (float4*)(ws + 4096);                      // 64*8*128 float4 = 1 MB
  float* cost = (float*)(ws + 4096 + (size_t)BB * NCH * QCH * sizeof(float4));  // ~24.6 MB

  cost_kernel<<<dim3(NCH, BB), 256, 0, stream>>>(logits, pboxes, gcls, gboxes, cost, part, acc);
  jv_kernel<<<BB, NT, 0, stream>>>(logits, pboxes, gcls, gboxes, cost, part, acc, (float*)d_out);
}